// Round 7
// baseline (900.956 us; speedup 1.0000x reference)
//
#include <hip/hip_runtime.h>

namespace {

constexpr int T_STEPS = 4096;
constexpr int NBATCH  = 2048;
constexpr int HID     = 10;
constexpr float L2E   = 1.4426950408889634f;

typedef float v2f __attribute__((ext_vector_type(2)));
typedef float v4f __attribute__((ext_vector_type(4)));

__device__ __forceinline__ float ex2(float x){ return __builtin_amdgcn_exp2f(x); }
__device__ __forceinline__ float rcp_(float x){ return __builtin_amdgcn_rcpf(x); }

template<int IMM>
__device__ __forceinline__ float swz(float v){
    return __int_as_float(__builtin_amdgcn_ds_swizzle(__float_as_int(v), IMM));
}
__device__ __forceinline__ float bperm(int addr, float v){
    return __int_as_float(__builtin_amdgcn_ds_bpermute(addr, __float_as_int(v)));
}
// DPP: empirically calibrated in R2/R3 — ctrl 0x100|N (row_shl:N) gives lane i <- lane i+N
// within its 16-lane row; bound_ctrl=true: out-of-row sources read 0.
template<int CTRL>
__device__ __forceinline__ float dpp(float v){
    return __int_as_float(__builtin_amdgcn_update_dpp(0, __float_as_int(v), CTRL, 0xF, 0xF, true));
}
__device__ __forceinline__ void pk_fma(v2f &a, v2f b, v2f c){
    asm("v_pk_fma_f32 %0, %1, %2, %0" : "+v"(a) : "v"(b), "v"(c));
}

// ---- 64 lanes = ONE batch (2048 waves total -> 2 waves/SIMD for latency hiding) ----
// Pair q = 2h+p, h in [0,10), p=0 -> gates {i,f}, p=1 -> gates {g,o}. Each lane owns 2 gate-rows.
// lanes  0-15 : L0  q=0..15     16-23: L1A q=0..7    24-31: L1B q=0..7
// lanes 32-39 : L1A q=8..15     40-47: L1B q=8..15
// lanes 48-51 : L1A q=16..19    52-55: L0  q=16..19  56-59: L1B q=16..19   60-63: pad
// L1B partner = L1A lane + 8 (same 16-row) -> combine via dpp row_shl:8.
// Gate merge: even lane (p=0, holds i,f) pulls (g,o) from lane+1 via dpp row_shl:1.
// Weights prescaled: i,f,o rows by -log2(e); g rows by +2log2(e) ->
//   sig = rcp(1+exp2(a)), tanh = fma(-2, rcp(1+exp2(a)), 1)  (one mul shorter chains).
// Skew: wave-step s computes L0 t=s, L1 t=s-1. h exchanged via per-wave LDS strip:
//   h0 -> slots 0..9, h1 -> slots 12..21 (16B-aligned base), non-owners -> trash 24+lane.

__device__ __forceinline__ void lstm_step(
    const v2f (&Wp)[2][5], float wx0, float wx1, float b0, float b1,
    float selA, float kA, float kB,
    float* hwp, const char* rdb,
    float &hn, float &c, float xv,
    float wlin, float blin, int t_l1, float* __restrict__ out, int b)
{
    *hwp = hn;                              // publish prev h (ds_write_b32)
    asm volatile("" ::: "memory");          // compiler fence (R5 lesson: wave_barrier is IntrNoMem)
    const v4f Va = *(const v4f*)(rdb);      // h[0..3]
    const v4f Vb = *(const v4f*)(rdb+16);   // h[4..7]
    const v2f Vc = *(const v2f*)(rdb+32);   // h[8..9]
    const v2f va01 = __builtin_shufflevector(Va, Va, 0, 1);
    const v2f va23 = __builtin_shufflevector(Va, Va, 2, 3);
    const v2f vb01 = __builtin_shufflevector(Vb, Vb, 0, 1);
    const v2f vb23 = __builtin_shufflevector(Vb, Vb, 2, 3);

    v2f A0 = { fmaf(wx0, xv, b0), 0.0f };   // bias + x-term in accumulator init
    v2f A1 = { fmaf(wx1, xv, b1), 0.0f };
    pk_fma(A0, Wp[0][0], va01);  pk_fma(A1, Wp[1][0], va01);
    pk_fma(A0, Wp[0][1], va23);  pk_fma(A1, Wp[1][1], va23);
    pk_fma(A0, Wp[0][2], vb01);  pk_fma(A1, Wp[1][2], vb01);
    pk_fma(A0, Wp[0][3], vb23);  pk_fma(A1, Wp[1][3], vb23);
    pk_fma(A0, Wp[0][4], Vc);    pk_fma(A1, Wp[1][4], Vc);
    float a0 = A0.x + A0.y;
    float a1 = A1.x + A1.y;

    // L1 half-combine: L1A lane += partner(L1B, +8) partial; others add 0
    a0 = fmaf(selA, dpp<0x108>(a0), a0);
    a1 = fmaf(selA, dpp<0x108>(a1), a1);

    // activations (prescaled): r = rcp(1+exp2(a))
    const float r0 = rcp_(1.0f + ex2(a0));
    const float r1 = rcp_(1.0f + ex2(a1));
    const float g0 = fmaf(kA, r0, kB);      // even: i = r0 (kA=1,kB=0); odd: g = 1-2r0
    const float g1 = r1;                    // even: f ; odd: o

    // even lane merges partner's (g,o)
    const float gv = dpp<0x101>(g0);
    const float ov = dpp<0x101>(g1);
    c = fmaf(g1, c, g0 * gv);               // even: c = f*c + i*g
    const float tc = fmaf(-2.0f, rcp_(1.0f + ex2(c * (2.0f*L2E))), 1.0f);  // tanh(c)
    hn = ov * tc;

    if (t_l1 >= T_STEPS-2) {                // uniform branch: true only at s=4095,4096
        float p = hn * wlin;                // wlin!=0 only on L1A-even (h1 owner) lanes
        p += swz<0x041F>(p); p += swz<0x081F>(p); p += swz<0x101F>(p);
        p += swz<0x201F>(p); p += swz<0x401F>(p);
        p += bperm((((int)threadIdx.x ^ 32) & 63)*4, p);   // cross-half
        if (threadIdx.x == 0)
            out[(t_l1 - (T_STEPS-2))*NBATCH + b] = p + blin;
    }
}

__device__ __forceinline__ float rdlane(float v, int lane){
    return __int_as_float(__builtin_amdgcn_readlane(__float_as_int(v), lane));
}

__global__ __launch_bounds__(64) void lstm2_kernel(
    const float* __restrict__ x,
    const float* __restrict__ Wih0, const float* __restrict__ Whh0,
    const float* __restrict__ bih0, const float* __restrict__ bhh0,
    const float* __restrict__ Wih1, const float* __restrict__ Whh1,
    const float* __restrict__ bih1, const float* __restrict__ bhh1,
    const float* __restrict__ Wlin, const float* __restrict__ blin_p,
    float* __restrict__ out)
{
    __shared__ float hx[96];                 // slots: 0-9 h0, 12-21 h1, 24+lane trash

    const int tid = (int)threadIdx.x;        // 0..63, one 64-lane wave = one batch
    const int b   = (int)blockIdx.x;         // batch index 0..2047

    // role decode: 0=L0, 1=L1A, 2=L1B, 3=pad
    int role, q;
    if      (tid < 16){ role=0; q=tid; }
    else if (tid < 24){ role=1; q=tid-16; }
    else if (tid < 32){ role=2; q=tid-24; }
    else if (tid < 40){ role=1; q=tid-32+8; }
    else if (tid < 48){ role=2; q=tid-40+8; }
    else if (tid < 52){ role=1; q=tid-48+16; }
    else if (tid < 56){ role=0; q=tid-52+16; }
    else if (tid < 60){ role=2; q=tid-56+16; }
    else              { role=3; q=0; }
    const int h = q >> 1, p = q & 1;
    const int gate0 = p ? 2 : 0, gate1 = p ? 3 : 1;     // torch order i,f,g,o
    const float s0 = (gate0 == 2) ? 2.0f*L2E : -L2E;    // prescale per gate
    const float s1 = -L2E;                              // f and o are both sigmoid

    float W0[HID], W1[HID], wx0=0.0f, wx1=0.0f, b0=0.0f, b1=0.0f;
    const int r0i = gate0*HID + h, r1i = gate1*HID + h;
    if (role == 0){
        #pragma unroll
        for (int j=0;j<HID;++j){ W0[j]=Whh0[r0i*HID+j]*s0; W1[j]=Whh0[r1i*HID+j]*s1; }
        wx0 = Wih0[r0i]*s0;  wx1 = Wih0[r1i]*s1;
        b0 = (bih0[r0i]+bhh0[r0i])*s0;  b1 = (bih0[r1i]+bhh0[r1i])*s1;
    } else if (role == 1){
        #pragma unroll
        for (int j=0;j<HID;++j){ W0[j]=Wih1[r0i*HID+j]*s0; W1[j]=Wih1[r1i*HID+j]*s1; }
        b0 = (bih1[r0i]+bhh1[r0i])*s0;  b1 = (bih1[r1i]+bhh1[r1i])*s1;
    } else if (role == 2){
        #pragma unroll
        for (int j=0;j<HID;++j){ W0[j]=Whh1[r0i*HID+j]*s0; W1[j]=Whh1[r1i*HID+j]*s1; }
        // bias lives on the L1A half
    } else {
        #pragma unroll
        for (int j=0;j<HID;++j){ W0[j]=0.0f; W1[j]=0.0f; }
    }
    v2f Wp[2][5];
    #pragma unroll
    for (int k=0;k<5;++k){ Wp[0][k]=v2f{W0[2*k],W0[2*k+1]}; Wp[1][k]=v2f{W1[2*k],W1[2*k+1]}; }

    const float selA = (role==1) ? 1.0f : 0.0f;
    const float kA = p ? -2.0f : 1.0f;      // gate0 post-map: sig (even) / tanh-form (odd)
    const float kB = p ?  1.0f : 0.0f;
    const bool owner = (p==0) && (role==0 || role==1);
    const int wslot = owner ? (role==0 ? h : 12+h) : (24+tid);
    float* hwp = &hx[wslot];
    const char* rdb = (const char*)hx + (role==2 ? 48 : 0);
    const float wlin = (role==1 && p==0) ? Wlin[h] : 0.0f;
    const float blin = blin_p[0];

    float hn = 0.0f, c = 0.0f;

    // x prefetch: lanes 0-7 hold x[8i+j] for this batch (others load duplicates, harmless)
    const float* xp = x + (size_t)(tid & 7) * NBATCH + b;
    float xpre = xp[0];

    // ---- peeled iteration 0 (s=0..7): L1 bias zeroed at s=0 so its fake t=-1
    //      step yields h=c=0 exactly (a=0 -> i=f=o=0.5, g=0, c_in=0).
    {
        const float zb0 = (role==0) ? b0 : 0.0f, zb1 = (role==0) ? b1 : 0.0f;
        lstm_step(Wp, wx0,wx1, zb0,zb1, selA,kA,kB, hwp,rdb, hn,c, rdlane(xpre,0), wlin,blin, -1, out, b);
        lstm_step(Wp, wx0,wx1, b0,b1, selA,kA,kB, hwp,rdb, hn,c, rdlane(xpre,1), wlin,blin, 0, out, b);
        lstm_step(Wp, wx0,wx1, b0,b1, selA,kA,kB, hwp,rdb, hn,c, rdlane(xpre,2), wlin,blin, 1, out, b);
        lstm_step(Wp, wx0,wx1, b0,b1, selA,kA,kB, hwp,rdb, hn,c, rdlane(xpre,3), wlin,blin, 2, out, b);
        lstm_step(Wp, wx0,wx1, b0,b1, selA,kA,kB, hwp,rdb, hn,c, rdlane(xpre,4), wlin,blin, 3, out, b);
        lstm_step(Wp, wx0,wx1, b0,b1, selA,kA,kB, hwp,rdb, hn,c, rdlane(xpre,5), wlin,blin, 4, out, b);
        lstm_step(Wp, wx0,wx1, b0,b1, selA,kA,kB, hwp,rdb, hn,c, rdlane(xpre,6), wlin,blin, 5, out, b);
        lstm_step(Wp, wx0,wx1, b0,b1, selA,kA,kB, hwp,rdb, hn,c, rdlane(xpre,7), wlin,blin, 6, out, b);
    }

    // ---- main loop: iterations 1..511 (s = 8..4095)
    for (int i=1; i<512; ++i){
        const float xcur = xp[(size_t)i*8*NBATCH];     // this iteration's 8 x values
        const int s0b = i*8;
        lstm_step(Wp, wx0,wx1, b0,b1, selA,kA,kB, hwp,rdb, hn,c, rdlane(xcur,0), wlin,blin, s0b-1, out, b);
        lstm_step(Wp, wx0,wx1, b0,b1, selA,kA,kB, hwp,rdb, hn,c, rdlane(xcur,1), wlin,blin, s0b+0, out, b);
        lstm_step(Wp, wx0,wx1, b0,b1, selA,kA,kB, hwp,rdb, hn,c, rdlane(xcur,2), wlin,blin, s0b+1, out, b);
        lstm_step(Wp, wx0,wx1, b0,b1, selA,kA,kB, hwp,rdb, hn,c, rdlane(xcur,3), wlin,blin, s0b+2, out, b);
        lstm_step(Wp, wx0,wx1, b0,b1, selA,kA,kB, hwp,rdb, hn,c, rdlane(xcur,4), wlin,blin, s0b+3, out, b);
        lstm_step(Wp, wx0,wx1, b0,b1, selA,kA,kB, hwp,rdb, hn,c, rdlane(xcur,5), wlin,blin, s0b+4, out, b);
        lstm_step(Wp, wx0,wx1, b0,b1, selA,kA,kB, hwp,rdb, hn,c, rdlane(xcur,6), wlin,blin, s0b+5, out, b);
        lstm_step(Wp, wx0,wx1, b0,b1, selA,kA,kB, hwp,rdb, hn,c, rdlane(xcur,7), wlin,blin, s0b+6, out, b);
    }

    // ---- epilogue wave-step s=4096: L1 computes t=4095 (L0 half computes unused junk, x=0)
    lstm_step(Wp, wx0,wx1, b0,b1, selA,kA,kB, hwp,rdb, hn,c, 0.0f, wlin,blin, T_STEPS-1, out, b);
}

} // anonymous namespace

extern "C" void kernel_launch(void* const* d_in, const int* in_sizes, int n_in,
                              void* d_out, int out_size, void* d_ws, size_t ws_size,
                              hipStream_t stream) {
    const float* x    = (const float*)d_in[0];
    const float* Wih0 = (const float*)d_in[1];
    const float* Whh0 = (const float*)d_in[2];
    const float* bih0 = (const float*)d_in[3];
    const float* bhh0 = (const float*)d_in[4];
    const float* Wih1 = (const float*)d_in[5];
    const float* Whh1 = (const float*)d_in[6];
    const float* bih1 = (const float*)d_in[7];
    const float* bhh1 = (const float*)d_in[8];
    const float* Wlin = (const float*)d_in[9];
    const float* blin = (const float*)d_in[10];
    float* out = (float*)d_out;

    // one 64-lane wave per batch: 2048 waves = 2 waves/SIMD chip-wide (latency hiding)
    hipLaunchKernelGGL(lstm2_kernel, dim3(NBATCH), dim3(64), 0, stream,
                       x, Wih0, Whh0, bih0, bhh0, Wih1, Whh1, bih1, bhh1, Wlin, blin, out);
}

// Round 8
// 817.350 us; speedup vs baseline: 1.1023x; 1.1023x over previous
//
#include <hip/hip_runtime.h>

namespace {

constexpr int T_STEPS = 4096;
constexpr int NBATCH  = 2048;
constexpr int HID     = 10;
constexpr float L2E   = 1.4426950408889634f;

typedef float v2f __attribute__((ext_vector_type(2)));
typedef float v4f __attribute__((ext_vector_type(4)));

__device__ __forceinline__ float ex2(float x){ return __builtin_amdgcn_exp2f(x); }
__device__ __forceinline__ float rcp_(float x){ return __builtin_amdgcn_rcpf(x); }

template<int IMM>
__device__ __forceinline__ float swz(float v){
    return __int_as_float(__builtin_amdgcn_ds_swizzle(__float_as_int(v), IMM));
}
__device__ __forceinline__ float bperm(int addr, float v){
    return __int_as_float(__builtin_amdgcn_ds_bpermute(addr, __float_as_int(v)));
}
// DPP (calibrated R2/R3): ctrl 0x100|N = lane i <- lane i+N within its 16-lane row.
template<int CTRL>
__device__ __forceinline__ float dpp(float v){
    return __int_as_float(__builtin_amdgcn_update_dpp(0, __float_as_int(v), CTRL, 0xF, 0xF, true));
}
__device__ __forceinline__ void pk_fma(v2f &a, v2f b, v2f c){
    asm("v_pk_fma_f32 %0, %1, %2, %0" : "+v"(a) : "v"(b), "v"(c));
}
__device__ __forceinline__ float rdlane(float v, int lane){
    return __int_as_float(__builtin_amdgcn_readlane(__float_as_int(v), lane));
}

// ---- 64 lanes = ONE batch; 2048 waves = 2 waves/SIMD ----
// Lane layout identical to R7 (debugged/passing). R8 changes ONLY the h-exchange
// schedule: DOUBLE-BUFFERED LDS strips — read prev-h at top of step from buf p,
// write new h at bottom to buf 1-p. Removes the same-step ds_write->ds_read
// serialization (~120cyc DS round trip) from the recurrence critical path.
// Strip layout (floats): buf0 @ 0..23 (h0:0-9, h1:12-21), buf1 @ 24..47,
// trash @ 48+tid. All read slots are owner slots; buf0 pre-zeroed (h(-1)=0).

__device__ __forceinline__ void lstm_step(
    const v2f (&Wp)[2][5], float wx0, float wx1, float b0, float b1,
    float selA, float kA, float kB,
    float* hwp, const char* rdb,
    float &hn, float &c, float xv,
    float wlin, float blin, int t_l1, float* __restrict__ out, int b)
{
    // read PREVIOUS step's h (other buffer — no dependence on this step's write)
    const v4f Va = *(const v4f*)(rdb);      // h[0..3]
    const v4f Vb = *(const v4f*)(rdb+16);   // h[4..7]
    const v2f Vc = *(const v2f*)(rdb+32);   // h[8..9]
    const v2f va01 = __builtin_shufflevector(Va, Va, 0, 1);
    const v2f va23 = __builtin_shufflevector(Va, Va, 2, 3);
    const v2f vb01 = __builtin_shufflevector(Vb, Vb, 0, 1);
    const v2f vb23 = __builtin_shufflevector(Vb, Vb, 2, 3);

    v2f A0 = { fmaf(wx0, xv, b0), 0.0f };   // bias + x-term in accumulator init
    v2f A1 = { fmaf(wx1, xv, b1), 0.0f };
    pk_fma(A0, Wp[0][0], va01);  pk_fma(A1, Wp[1][0], va01);
    pk_fma(A0, Wp[0][1], va23);  pk_fma(A1, Wp[1][1], va23);
    pk_fma(A0, Wp[0][2], vb01);  pk_fma(A1, Wp[1][2], vb01);
    pk_fma(A0, Wp[0][3], vb23);  pk_fma(A1, Wp[1][3], vb23);
    pk_fma(A0, Wp[0][4], Vc);    pk_fma(A1, Wp[1][4], Vc);
    float a0 = A0.x + A0.y;
    float a1 = A1.x + A1.y;

    // L1 half-combine: L1A lane += partner(L1B, +8) partial; others add 0
    a0 = fmaf(selA, dpp<0x108>(a0), a0);
    a1 = fmaf(selA, dpp<0x108>(a1), a1);

    // activations (weights prescaled by -log2e / +2log2e): r = rcp(1+exp2(a))
    const float r0 = rcp_(1.0f + ex2(a0));
    const float r1 = rcp_(1.0f + ex2(a1));
    const float g0 = fmaf(kA, r0, kB);      // even: i ; odd: g = 1-2r
    const float g1 = r1;                    // even: f ; odd: o

    // even lane merges partner's (g,o)
    const float gv = dpp<0x101>(g0);
    const float ov = dpp<0x101>(g1);
    c = fmaf(g1, c, g0 * gv);               // even: c = f*c + i*g
    const float tc = fmaf(-2.0f, rcp_(1.0f + ex2(c * (2.0f*L2E))), 1.0f);  // tanh(c)
    hn = ov * tc;

    *hwp = hn;                              // publish to the OTHER buffer
    asm volatile("" ::: "memory");          // compiler fence (R5 lesson)

    if (t_l1 >= T_STEPS-2) {                // uniform branch: true only at s=4095,4096
        float p = hn * wlin;                // wlin!=0 only on L1A-even (h1 owner) lanes
        p += swz<0x041F>(p); p += swz<0x081F>(p); p += swz<0x101F>(p);
        p += swz<0x201F>(p); p += swz<0x401F>(p);
        p += bperm((((int)threadIdx.x ^ 32) & 63)*4, p);   // cross-half
        if (threadIdx.x == 0)
            out[(t_l1 - (T_STEPS-2))*NBATCH + b] = p + blin;
    }
}

__global__ __launch_bounds__(64) void lstm2_kernel(
    const float* __restrict__ x,
    const float* __restrict__ Wih0, const float* __restrict__ Whh0,
    const float* __restrict__ bih0, const float* __restrict__ bhh0,
    const float* __restrict__ Wih1, const float* __restrict__ Whh1,
    const float* __restrict__ bih1, const float* __restrict__ bhh1,
    const float* __restrict__ Wlin, const float* __restrict__ blin_p,
    float* __restrict__ out)
{
    __shared__ __attribute__((aligned(16))) float hx[128];  // buf0 0..23, buf1 24..47, trash 48+tid

    const int tid = (int)threadIdx.x;        // 0..63, one 64-lane wave = one batch
    const int b   = (int)blockIdx.x;         // batch index 0..2047

    // role decode (identical to R7): 0=L0, 1=L1A, 2=L1B, 3=pad
    int role, q;
    if      (tid < 16){ role=0; q=tid; }
    else if (tid < 24){ role=1; q=tid-16; }
    else if (tid < 32){ role=2; q=tid-24; }
    else if (tid < 40){ role=1; q=tid-32+8; }
    else if (tid < 48){ role=2; q=tid-40+8; }
    else if (tid < 52){ role=1; q=tid-48+16; }
    else if (tid < 56){ role=0; q=tid-52+16; }
    else if (tid < 60){ role=2; q=tid-56+16; }
    else              { role=3; q=0; }
    const int h = q >> 1, p = q & 1;
    const int gate0 = p ? 2 : 0, gate1 = p ? 3 : 1;     // torch order i,f,g,o
    const float s0 = (gate0 == 2) ? 2.0f*L2E : -L2E;    // prescale per gate
    const float s1 = -L2E;

    float W0[HID], W1[HID], wx0=0.0f, wx1=0.0f, b0=0.0f, b1=0.0f;
    const int r0i = gate0*HID + h, r1i = gate1*HID + h;
    if (role == 0){
        #pragma unroll
        for (int j=0;j<HID;++j){ W0[j]=Whh0[r0i*HID+j]*s0; W1[j]=Whh0[r1i*HID+j]*s1; }
        wx0 = Wih0[r0i]*s0;  wx1 = Wih0[r1i]*s1;
        b0 = (bih0[r0i]+bhh0[r0i])*s0;  b1 = (bih0[r1i]+bhh0[r1i])*s1;
    } else if (role == 1){
        #pragma unroll
        for (int j=0;j<HID;++j){ W0[j]=Wih1[r0i*HID+j]*s0; W1[j]=Wih1[r1i*HID+j]*s1; }
        b0 = (bih1[r0i]+bhh1[r0i])*s0;  b1 = (bih1[r1i]+bhh1[r1i])*s1;
    } else if (role == 2){
        #pragma unroll
        for (int j=0;j<HID;++j){ W0[j]=Whh1[r0i*HID+j]*s0; W1[j]=Whh1[r1i*HID+j]*s1; }
    } else {
        #pragma unroll
        for (int j=0;j<HID;++j){ W0[j]=0.0f; W1[j]=0.0f; }
    }
    v2f Wp[2][5];
    #pragma unroll
    for (int k=0;k<5;++k){ Wp[0][k]=v2f{W0[2*k],W0[2*k+1]}; Wp[1][k]=v2f{W1[2*k],W1[2*k+1]}; }

    const float selA = (role==1) ? 1.0f : 0.0f;
    const float kA = p ? -2.0f : 1.0f;
    const float kB = p ?  1.0f : 0.0f;
    const bool owner = (p==0) && (role==0 || role==1);
    const int slot = owner ? (role==0 ? h : 12+h) : -1;

    // double-buffer pointers: even step s reads buf0 / writes buf1; odd: reverse
    float* hwpE = &hx[slot >= 0 ? 24+slot : 48+tid];     // write target at even s
    float* hwpO = &hx[slot >= 0 ?    slot : 48+tid];     // write target at odd s
    const char* rdbE = (const char*)hx + (role==2 ? 48 : 0);          // read buf0
    const char* rdbO = (const char*)hx + 96 + (role==2 ? 48 : 0);     // read buf1
    const float wlin = (role==1 && p==0) ? Wlin[h] : 0.0f;
    const float blin = blin_p[0];

    // pre-zero both buffers' owner slots (buf0 is read at s=0; harness poisons LDS)
    hx[slot >= 0 ? slot : 48+tid] = 0.0f;
    hx[slot >= 0 ? 24+slot : 48+tid] = 0.0f;
    asm volatile("" ::: "memory");

    float hn = 0.0f, c = 0.0f;

    // x prefetch: lanes 0-7 hold x[8i+j] for this batch (others load duplicates)
    const float* xp = x + (size_t)(tid & 7) * NBATCH + b;
    float xcur = xp[0];
    float xnxt = xp[(size_t)8 * NBATCH];

    // ---- peeled iteration 0 (s=0..7): L1 bias zeroed at s=0 so its fake t=-1
    //      step yields h=c=0 exactly (reads h=0 from zeroed buf0, a=0 -> c=0,h=0).
    {
        const float zb0 = (role==0) ? b0 : 0.0f, zb1 = (role==0) ? b1 : 0.0f;
        lstm_step(Wp, wx0,wx1, zb0,zb1, selA,kA,kB, hwpE,rdbE, hn,c, rdlane(xcur,0), wlin,blin, -1, out, b);
        lstm_step(Wp, wx0,wx1, b0,b1, selA,kA,kB, hwpO,rdbO, hn,c, rdlane(xcur,1), wlin,blin, 0, out, b);
        lstm_step(Wp, wx0,wx1, b0,b1, selA,kA,kB, hwpE,rdbE, hn,c, rdlane(xcur,2), wlin,blin, 1, out, b);
        lstm_step(Wp, wx0,wx1, b0,b1, selA,kA,kB, hwpO,rdbO, hn,c, rdlane(xcur,3), wlin,blin, 2, out, b);
        lstm_step(Wp, wx0,wx1, b0,b1, selA,kA,kB, hwpE,rdbE, hn,c, rdlane(xcur,4), wlin,blin, 3, out, b);
        lstm_step(Wp, wx0,wx1, b0,b1, selA,kA,kB, hwpO,rdbO, hn,c, rdlane(xcur,5), wlin,blin, 4, out, b);
        lstm_step(Wp, wx0,wx1, b0,b1, selA,kA,kB, hwpE,rdbE, hn,c, rdlane(xcur,6), wlin,blin, 5, out, b);
        lstm_step(Wp, wx0,wx1, b0,b1, selA,kA,kB, hwpO,rdbO, hn,c, rdlane(xcur,7), wlin,blin, 6, out, b);
    }

    // ---- main loop: iterations 1..511 (s = 8..4095); 8 steps/iter keeps parity pattern fixed
    for (int i=1; i<512; ++i){
        xcur = xnxt;
        if (i < 511) xnxt = xp[(size_t)(i+1)*8*NBATCH];   // prefetch next 8 timesteps
        const int s0b = i*8;
        lstm_step(Wp, wx0,wx1, b0,b1, selA,kA,kB, hwpE,rdbE, hn,c, rdlane(xcur,0), wlin,blin, s0b-1, out, b);
        lstm_step(Wp, wx0,wx1, b0,b1, selA,kA,kB, hwpO,rdbO, hn,c, rdlane(xcur,1), wlin,blin, s0b+0, out, b);
        lstm_step(Wp, wx0,wx1, b0,b1, selA,kA,kB, hwpE,rdbE, hn,c, rdlane(xcur,2), wlin,blin, s0b+1, out, b);
        lstm_step(Wp, wx0,wx1, b0,b1, selA,kA,kB, hwpO,rdbO, hn,c, rdlane(xcur,3), wlin,blin, s0b+2, out, b);
        lstm_step(Wp, wx0,wx1, b0,b1, selA,kA,kB, hwpE,rdbE, hn,c, rdlane(xcur,4), wlin,blin, s0b+3, out, b);
        lstm_step(Wp, wx0,wx1, b0,b1, selA,kA,kB, hwpO,rdbO, hn,c, rdlane(xcur,5), wlin,blin, s0b+4, out, b);
        lstm_step(Wp, wx0,wx1, b0,b1, selA,kA,kB, hwpE,rdbE, hn,c, rdlane(xcur,6), wlin,blin, s0b+5, out, b);
        lstm_step(Wp, wx0,wx1, b0,b1, selA,kA,kB, hwpO,rdbO, hn,c, rdlane(xcur,7), wlin,blin, s0b+6, out, b);
    }

    // ---- epilogue wave-step s=4096 (even parity): L1 computes t=4095
    lstm_step(Wp, wx0,wx1, b0,b1, selA,kA,kB, hwpE,rdbE, hn,c, 0.0f, wlin,blin, T_STEPS-1, out, b);
}

} // anonymous namespace

extern "C" void kernel_launch(void* const* d_in, const int* in_sizes, int n_in,
                              void* d_out, int out_size, void* d_ws, size_t ws_size,
                              hipStream_t stream) {
    const float* x    = (const float*)d_in[0];
    const float* Wih0 = (const float*)d_in[1];
    const float* Whh0 = (const float*)d_in[2];
    const float* bih0 = (const float*)d_in[3];
    const float* bhh0 = (const float*)d_in[4];
    const float* Wih1 = (const float*)d_in[5];
    const float* Whh1 = (const float*)d_in[6];
    const float* bih1 = (const float*)d_in[7];
    const float* bhh1 = (const float*)d_in[8];
    const float* Wlin = (const float*)d_in[9];
    const float* blin = (const float*)d_in[10];
    float* out = (float*)d_out;

    // one 64-lane wave per batch: 2048 waves = 2 waves/SIMD chip-wide
    hipLaunchKernelGGL(lstm2_kernel, dim3(NBATCH), dim3(64), 0, stream,
                       x, Wih0, Whh0, bih0, bhh0, Wih1, Whh1, bih1, bhh1, Wlin, blin, out);
}